// Round 9
// baseline (444.498 us; speedup 1.0000x reference)
//
#include <hip/hip_runtime.h>
#include <hip/hip_bf16.h>
#include <stdint.h>

// Problem constants (fixed by setup_inputs)
#define NTOK   8192
#define TOPK   2
#define NEXP   8
#define DIN    2048
#define DOUT   2048
#define NK     (NTOK*TOPK)

// GEMM tiling: 256(M) x 128(N) tile, BK=32, FOUR waves as 2(M) x 2(N),
// wave tile 128x64 = 8x4 MFMA 16x16x32 bf16 frags.
// LDS-ECONOMY LESSON (R8 accounting): the kernel is LDS-port-bound, and LDS
// bytes/FLOP depend only on wave-tile size. 64x64 wave tile: 88 KB/block-tile;
// 128x64: 72 KB (-18%). Wave tile is register-capped: 128-reg acc needs the
// 256-reg/wave budget of 2 waves/SIMD -> 256-thread block, launch_bounds(256,2)
// (R5's spill was the 4-waves/SIMD 128-reg cap, not the acc itself).
// SHAPE LESSON (R7): 32x32x16 frags -> 4-way LDS bank conflict (1.78e7); the
// 16-row frag pattern below measures ZERO conflicts.
// OCCUPANCY LESSON (R1/R2/R4): 1-block/CU lockstep loses ~6pts MfmaUtil; keep
// 2 blocks/CU (LDS 75776 B x 2 <= 160 KB).
#define BM 256
#define BN 128
#define BK 32
#define KTILES  (DIN/BK)           // 64
#define SLOT    24576              // per-K-tile LDS: A 16 KB + B 8 KB
#define NBUF    3                  // 72 KB ring, prefetch depth 2 tiles

typedef __bf16 bf16_8 __attribute__((ext_vector_type(8)));  // 4 VGPRs, MFMA A/B frag
typedef float  f32x4  __attribute__((ext_vector_type(4)));  // MFMA C/D frag

// global->LDS direct load, 16B per lane. LDS dest = wave-uniform base + lane*16.
__device__ __forceinline__ void gl2lds16(const void* g, void* l) {
  auto gp = reinterpret_cast<const __attribute__((address_space(1))) uint32_t*>(
      reinterpret_cast<uintptr_t>(g));
  auto lp = reinterpret_cast<__attribute__((address_space(3))) uint32_t*>(
      reinterpret_cast<uintptr_t>(l));
  __builtin_amdgcn_global_load_lds(gp, lp, 16, 0, 0);
}

// Fused fp32 -> bf16 (RNE) for W then X. 8 elems/thread, 16B stores.
__global__ void cvt_all(const float4* __restrict__ w, uint4* __restrict__ wD,
                        const float4* __restrict__ x, uint4* __restrict__ xD,
                        int nW) {
  int b = blockIdx.x;
  const float4* src;
  uint4* dst;
  int i;
  if (b < nW) { src = w; dst = wD; i = b * 256 + threadIdx.x; }
  else        { src = x; dst = xD; i = (b - nW) * 256 + threadIdx.x; }
  float4 a0 = src[2 * i];
  float4 a1 = src[2 * i + 1];
  union { __bf16 h[8]; uint4 u; } r;
  r.h[0] = (__bf16)a0.x; r.h[1] = (__bf16)a0.y; r.h[2] = (__bf16)a0.z; r.h[3] = (__bf16)a0.w;
  r.h[4] = (__bf16)a1.x; r.h[5] = (__bf16)a1.y; r.h[6] = (__bf16)a1.z; r.h[7] = (__bf16)a1.w;
  dst[i] = r.u;
}

// Grouped GEMM over expert-sorted flat rows — R3/R8 ring schedule + XCD
// swizzle (FETCH 288->188 MB proven), re-waved to 4x(128x64) for LDS economy.
//
// Per K-tile t (counted-vmcnt NBUF=3 ring; 6 gl2lds calls/tile at 256 thr):
//   stage(t+2) -> slot (t+2)%3   (WAR-safe: slot (t-1)%3's reads were
//                                 consumed before end-of-(t-1) barrier)
//   ds_read af[0..7], bf[0..3] of tile t; 32 x MFMA 16x16x32
//   s_waitcnt vmcnt(6)           (tile t+1 landed; t+2's 6 stay in flight)
//   s_barrier
// Tail: vmcnt(0) at t=KTILES-2; no sync after last tile.
//
// LDS bank-conflict swizzle (measured 0 conflicts in this form): row r's 16B
// chunk q lives at chunk slot q ^ s(r), s(r) = (r>>1)&3. Staging thread tid
// writes LDS linear (row=tid>>2 in its region, slot=tid&3) and loads global
// chunk (tid&3)^((tid>>3)&3) = slot^s(row); reader xors kq by (lr>>1)&3.
__global__ __launch_bounds__(256, 2)
void moe_gemm(const __bf16* __restrict__ X,     // [NTOK, DIN] bf16
              const __bf16* __restrict__ W,     // [NEXP, DOUT, DIN] bf16 (B^T form)
              const int* __restrict__ ssi,      // sorted_scattered_idxs [NK]
              const int* __restrict__ offs,     // expert_offsets [NEXP]
              __bf16* __restrict__ flat)        // [NK, DOUT] bf16 out (ungated)
{
  __shared__ char lds[NBUF * SLOT];   // 72 KB ring: per slot A 16 KB | B 8 KB
  __shared__ int  sTok[BM];
  __shared__ int  sF[BM];

  const int tid = threadIdx.x;
  // XCD swizzle: HW assigns XCD = blockIdx % 8; remap so one XCD owns a
  // contiguous chunk of work ids -> same-mtg blocks share an L2. 1152%8==0.
  const int nwg = gridDim.x;
  const int b0  = blockIdx.x;
  const int bid = (b0 & 7) * (nwg >> 3) + (b0 >> 3);
  const int nt  = bid & 15;         // 16 N-tiles of 128
  const int mtg = bid >> 4;         // linear M-tile over all experts

  // Map linear M-tile -> (expert e, tile-in-segment). Uniform scan of 8 offsets.
  int start = 0, end = 0, e, cum = 0, prev = 0, mloc = 0, found = 0;
  for (e = 0; e < NEXP; ++e) {
    int oe  = offs[e];
    int seg = oe - prev;
    int t   = (seg + BM - 1) >> 8;
    if (mtg < cum + t) { start = prev; end = oe; mloc = mtg - cum; found = 1; break; }
    cum += t; prev = oe;
  }
  if (!found) return;  // pad block (uniform exit)

  const int m0 = start + mloc * BM;

  {
    int p     = m0 + tid;
    int valid = p < end;
    int f     = ssi[valid ? p : (end - 1)];  // clamp keeps gather in-bounds
    sTok[tid] = f >> 1;                      // token = flat / k (k=2)
    sF[tid]   = valid ? f : -1;
  }
  __syncthreads();   // tables visible; full drain -> clean slate for counted regime

  // Staging: thread tid owns A rows rs, rs+64, rs+128, rs+192 and B rows
  // rs, rs+64 (rs = tid>>2, 0..63), swizzled k-chunk kc. 6 gl2lds calls of
  // 4 KB each; LDS dest linear: region base + wave slice + lane*16 = tid*16.
  const int rs = tid >> 2;                       // 0..63
  const int kc = (tid & 3) ^ ((tid >> 3) & 3);   // swizzled chunk
  const __bf16* pA0 = X + (size_t)sTok[rs]       * DIN + kc * 8;
  const __bf16* pA1 = X + (size_t)sTok[rs + 64]  * DIN + kc * 8;
  const __bf16* pA2 = X + (size_t)sTok[rs + 128] * DIN + kc * 8;
  const __bf16* pA3 = X + (size_t)sTok[rs + 192] * DIN + kc * 8;
  const __bf16* wBp = W + (size_t)e * DOUT * DIN + (size_t)(nt * BN) * DIN;
  const __bf16* pB0 = wBp + (size_t)rs * DIN + kc * 8;
  const __bf16* pB1 = wBp + (size_t)(rs + 64) * DIN + kc * 8;
  char* wsl = (char*)lds + (tid >> 6) * 1024;    // wave-uniform slice base

#define STAGE(base)                                              \
  do {                                                           \
    gl2lds16(pA0, (base));          gl2lds16(pA1, (base) + 4096);  \
    gl2lds16(pA2, (base) + 8192);   gl2lds16(pA3, (base) + 12288); \
    gl2lds16(pB0, (base) + 16384);  gl2lds16(pB1, (base) + 20480); \
    pA0 += BK; pA1 += BK; pA2 += BK; pA3 += BK; pB0 += BK; pB1 += BK; \
  } while (0)

  // Prologue: stage tiles 0,1 into slots 0,1 (12 loads in flight).
  STAGE(wsl);
  STAGE(wsl + SLOT);

  // Fragment addressing. Wave grid 2(M) x 2(N); wave tile 128 x 64.
  // A frag i: rows wm*128 + i*16 + lr; B frag i: cols wn*64 + i*16 + lr.
  const int w   = tid >> 6;
  const int l   = tid & 63;
  const int wm  = w >> 1, wn = w & 1;
  const int lr  = l & 15;
  const int kq  = l >> 4;
  const int kqs = kq ^ ((lr >> 1) & 3);          // bank-conflict swizzle
  const char* aBase = (const char*)lds + (wm * 128 + lr) * 64 + kqs * 16;
  const char* bBase = (const char*)lds + 16384 + (wn * 64 + lr) * 64 + kqs * 16;

  // Tile 0 arrival: own 6 oldest loads done (tile 1's may stay in flight).
  asm volatile("s_waitcnt vmcnt(6)" ::: "memory");
  __builtin_amdgcn_s_barrier();

  f32x4 acc[8][4] = {};
  int rOff = 0;               // read slot byte offset (t % 3)
  int sOff = 2 * SLOT;        // stage slot byte offset ((t+2) % 3)

  for (int t = 0; t < KTILES; ++t) {
    // Issue next prefetch first (maximizes cover; 6 VMEM issues are cheap).
    if (t < KTILES - 2) {
      char* d = wsl + sOff;
      STAGE(d);
      sOff = (sOff == (NBUF - 1) * SLOT) ? 0 : sOff + SLOT;
    }

    const char* aB = aBase + rOff;
    const char* bB = bBase + rOff;
    rOff = (rOff == (NBUF - 1) * SLOT) ? 0 : rOff + SLOT;

    bf16_8 af[8], bf[4];
#pragma unroll
    for (int i = 0; i < 8; ++i) af[i] = *(const bf16_8*)(aB + i * 1024);  // rows i*16
#pragma unroll
    for (int i = 0; i < 4; ++i) bf[i] = *(const bf16_8*)(bB + i * 1024);  // cols i*16

#pragma unroll
    for (int am = 0; am < 8; ++am)
#pragma unroll
      for (int bn = 0; bn < 4; ++bn)
        acc[am][bn] = __builtin_amdgcn_mfma_f32_16x16x32_bf16(
            af[am], bf[bn], acc[am][bn], 0, 0, 0);

    // Arrival of tile t+1 for next iteration; never drain until the tail.
    if (t < KTILES - 2)       { asm volatile("s_waitcnt vmcnt(6)" ::: "memory"); }
    else if (t == KTILES - 2) { asm volatile("s_waitcnt vmcnt(0)" ::: "memory"); }
    if (t < KTILES - 1) __builtin_amdgcn_s_barrier();
  }
#undef STAGE

  // Epilogue: C/D layout col=lane&15, row=(lane>>4)*4+reg.
  // Plain bf16 stores, ungated; gate applied in combine kernel.
  const int colBase = nt * BN + wn * 64 + lr;
  const int rq = kq * 4;
#pragma unroll
  for (int am = 0; am < 8; ++am) {
#pragma unroll
    for (int v = 0; v < 4; ++v) {
      int rl = wm * 128 + am * 16 + rq + v;
      int f  = sF[rl];
      if (f < 0) continue;
      __bf16* row = flat + (size_t)f * DOUT + colBase;
#pragma unroll
      for (int bn = 0; bn < 4; ++bn)
        row[bn * 16] = (__bf16)acc[am][bn][v];
    }
  }
}

// out[n, :] = g[2n]*flat[2n, :] + g[2n+1]*flat[2n+1, :]
__global__ __launch_bounds__(256)
void combine(const __bf16* __restrict__ flat, const float* __restrict__ gates,
             float* __restrict__ out) {
  const int n = blockIdx.x;
  const int c = threadIdx.x * 8;
  bf16_8 y0 = *(const bf16_8*)(flat + (size_t)(2 * n)     * DOUT + c);
  bf16_8 y1 = *(const bf16_8*)(flat + (size_t)(2 * n + 1) * DOUT + c);
  const float2 g = *(const float2*)(gates + 2 * n);
  float o[8];
#pragma unroll
  for (int j = 0; j < 8; ++j)
    o[j] = g.x * (float)y0[j] + g.y * (float)y1[j];
  float4* dst = (float4*)(out + (size_t)n * DOUT + c);
  dst[0] = *(float4*)&o[0];
  dst[1] = *(float4*)&o[4];
}

extern "C" void kernel_launch(void* const* d_in, const int* in_sizes, int n_in,
                              void* d_out, int out_size, void* d_ws, size_t ws_size,
                              hipStream_t stream) {
  const float* inputs = (const float*)d_in[0];   // [8192, 2048]
  const float* ew     = (const float*)d_in[1];   // [8, 2048, 2048] (E, out, in)
  const float* gates  = (const float*)d_in[2];   // [8192, 2]
  const int*   ssi    = (const int*)d_in[5];     // sorted_scattered_idxs [16384]
  const int*   offs   = (const int*)d_in[6];     // expert_offsets [8]
  float* out = (float*)d_out;

  // ws layout: bf16 W (64 MB) | bf16 X (32 MB) | bf16 flat out (64 MB)
  __bf16* wsW = (__bf16*)d_ws;
  __bf16* wsX = wsW + (size_t)NEXP * DOUT * DIN;
  __bf16* wsF = wsX + (size_t)NTOK * DIN;

  const int n8w = NEXP * DOUT * DIN / 8;   // 4194304 -> 16384 blocks
  const int n8x = NTOK * DIN / 8;          // 2097152 ->  8192 blocks
  const int nWb = n8w / 256, nXb = n8x / 256;
  cvt_all<<<nWb + nXb, 256, 0, stream>>>((const float4*)ew, (uint4*)wsW,
                                         (const float4*)inputs, (uint4*)wsX, nWb);

  // max M-tiles = 64 + 8 (per-expert ceil padding), 16 N-tiles of 128
  moe_gemm<<<72 * 16, 256, 0, stream>>>(wsX, wsW, ssi, offs, wsF);
  combine<<<NTOK, 256, 0, stream>>>(wsF, gates, out);
}

// Round 10
// 434.262 us; speedup vs baseline: 1.0236x; 1.0236x over previous
//
#include <hip/hip_runtime.h>
#include <hip/hip_bf16.h>
#include <stdint.h>

// Problem constants (fixed by setup_inputs)
#define NTOK   8192
#define TOPK   2
#define NEXP   8
#define DIN    2048
#define DOUT   2048
#define NK     (NTOK*TOPK)

// GEMM tiling: 256(M) x 128(N) tile, BK=32, 8 waves as 4(M) x 2(N),
// wave tile 64x64 = 4x4 MFMA 16x16x32 bf16 frags.
// CONVERGED CONFIG (R0-R9 search):
// - SHAPE (R7): 32x32x16 frags -> 4-way LDS bank conflict (1.78e7, -8%);
//   this 16-row frag pattern measures ZERO conflicts.
// - REGISTERS (R5/R9): 128-reg acc either spills (4 waves/SIMD cap) or
//   halves occupancy (2 waves/SIMD) and goes latency-bound (R9: 188 us,
//   Occ 16%). 64-reg acc + 4 waves/SIMD is the feasible optimum.
// - OCCUPANCY (R1/R2/R4): 1-block/CU lockstep caps at ~33% MfmaUtil; the
//   gather's latency stragglers need a co-resident block. Keep 2 blocks/CU.
// - SCHEDULE (R3): counted-vmcnt NBUF=3 ring, one barrier + one vmcnt(3)
//   per K-tile, never draining until the tail.
// - XCD swizzle (R6/R8): FETCH 288 -> ~188 MB; kept (free L2 locality).
#define BM 256
#define BN 128
#define BK 32
#define KTILES  (DIN/BK)           // 64
#define SLOT    24576              // per-K-tile LDS: A 16 KB + B 8 KB
#define NBUF    3                  // 72 KB ring, prefetch depth 2 tiles

typedef __bf16 bf16_8 __attribute__((ext_vector_type(8)));  // 4 VGPRs, MFMA A/B frag
typedef float  f32x4  __attribute__((ext_vector_type(4)));  // MFMA C/D frag

// global->LDS direct load, 16B per lane. LDS dest = wave-uniform base + lane*16.
__device__ __forceinline__ void gl2lds16(const void* g, void* l) {
  auto gp = reinterpret_cast<const __attribute__((address_space(1))) uint32_t*>(
      reinterpret_cast<uintptr_t>(g));
  auto lp = reinterpret_cast<__attribute__((address_space(3))) uint32_t*>(
      reinterpret_cast<uintptr_t>(l));
  __builtin_amdgcn_global_load_lds(gp, lp, 16, 0, 0);
}

// Fused fp32 -> bf16 (RNE) for W then X. 8 elems/thread, 16B stores.
__global__ void cvt_all(const float4* __restrict__ w, uint4* __restrict__ wD,
                        const float4* __restrict__ x, uint4* __restrict__ xD,
                        int nW) {
  int b = blockIdx.x;
  const float4* src;
  uint4* dst;
  int i;
  if (b < nW) { src = w; dst = wD; i = b * 256 + threadIdx.x; }
  else        { src = x; dst = xD; i = (b - nW) * 256 + threadIdx.x; }
  float4 a0 = src[2 * i];
  float4 a1 = src[2 * i + 1];
  union { __bf16 h[8]; uint4 u; } r;
  r.h[0] = (__bf16)a0.x; r.h[1] = (__bf16)a0.y; r.h[2] = (__bf16)a0.z; r.h[3] = (__bf16)a0.w;
  r.h[4] = (__bf16)a1.x; r.h[5] = (__bf16)a1.y; r.h[6] = (__bf16)a1.z; r.h[7] = (__bf16)a1.w;
  dst[i] = r.u;
}

// Grouped GEMM over expert-sorted flat rows — R3 schedule + shape (166 us /
// 39.4% MfmaUtil / 0 LDS conflicts) + XCD-aware bijective block swizzle
// (FETCH 288 -> ~188 MB; same-mtg blocks share an L2).
//
// Per K-tile t (counted-vmcnt NBUF=3 ring):
//   stage(t+2) -> slot (t+2)%3   (3 gload_lds; WAR-safe: slot (t-1)%3's
//                                 reads were consumed before end-of-(t-1)
//                                 barrier, and this issue is after it)
//   ds_read af[0..3], bf[0..3] of tile t; 16 x MFMA 16x16x32
//   s_waitcnt vmcnt(3)           (tile t+1 landed; t+2's 3 stay in flight)
//   s_barrier
// Tail: vmcnt(0) at t=KTILES-2; no sync after last tile.
//
// LDS bank-conflict swizzle (measured 0 conflicts in this exact form):
// row r's 16B chunk q lives at chunk slot q ^ s(r), s(r) = (r>>1)&3.
// Staging lane loads global chunk (tid&3)^((tid>>3)&3); reader xors kq by
// (lr>>1)&3. s(r) invariant under r += multiples of 8.
__global__ __launch_bounds__(512, 4)
void moe_gemm(const __bf16* __restrict__ X,     // [NTOK, DIN] bf16
              const __bf16* __restrict__ W,     // [NEXP, DOUT, DIN] bf16 (B^T form)
              const int* __restrict__ ssi,      // sorted_scattered_idxs [NK]
              const int* __restrict__ offs,     // expert_offsets [NEXP]
              __bf16* __restrict__ flat)        // [NK, DOUT] bf16 out (ungated)
{
  __shared__ char lds[NBUF * SLOT];   // 72 KB ring: per slot A 16 KB | B 8 KB
  __shared__ int  sTok[BM];
  __shared__ int  sF[BM];

  const int tid = threadIdx.x;
  // XCD swizzle: HW assigns XCD = blockIdx % 8; remap so one XCD owns a
  // contiguous chunk of work ids -> same-mtg blocks share an L2. 1152%8==0.
  const int nwg = gridDim.x;
  const int b0  = blockIdx.x;
  const int bid = (b0 & 7) * (nwg >> 3) + (b0 >> 3);
  const int nt  = bid & 15;         // 16 N-tiles of 128
  const int mtg = bid >> 4;         // linear M-tile over all experts

  // Map linear M-tile -> (expert e, tile-in-segment). Uniform scan of 8 offsets.
  int start = 0, end = 0, e, cum = 0, prev = 0, mloc = 0, found = 0;
  for (e = 0; e < NEXP; ++e) {
    int oe  = offs[e];
    int seg = oe - prev;
    int t   = (seg + BM - 1) >> 8;
    if (mtg < cum + t) { start = prev; end = oe; mloc = mtg - cum; found = 1; break; }
    cum += t; prev = oe;
  }
  if (!found) return;  // pad block (uniform exit)

  const int m0 = start + mloc * BM;

  if (tid < BM) {
    int p     = m0 + tid;
    int valid = p < end;
    int f     = ssi[valid ? p : (end - 1)];  // clamp keeps gather in-bounds
    sTok[tid] = f >> 1;                      // token = flat / k (k=2)
    sF[tid]   = valid ? f : -1;
  }
  __syncthreads();   // tables visible; full drain -> clean slate for counted regime

  // Staging: thread tid owns A rows rs = tid>>2 and rs+128, B row rs,
  // swizzled k-chunk kc. LDS dest linear: wave slice base + lane*16.
  const int rs = tid >> 2;                       // 0..127
  const int kc = (tid & 3) ^ ((tid >> 3) & 3);   // swizzled chunk
  const __bf16* pA0 = X + (size_t)sTok[rs]       * DIN + kc * 8;
  const __bf16* pA1 = X + (size_t)sTok[rs + 128] * DIN + kc * 8;
  const __bf16* wBp = W + (size_t)e * DOUT * DIN + (size_t)(nt * BN) * DIN;
  const __bf16* pB0 = wBp + (size_t)rs * DIN + kc * 8;
  char* wsl = (char*)lds + (tid >> 6) * 1024;    // wave-uniform slice base

  // Prologue: stage tiles 0,1 into slots 0,1 (6 loads in flight).
  gl2lds16(pA0, wsl);           gl2lds16(pA1, wsl + 8192);
  gl2lds16(pB0, wsl + 16384);
  pA0 += BK; pA1 += BK; pB0 += BK;
  gl2lds16(pA0, wsl + SLOT);    gl2lds16(pA1, wsl + SLOT + 8192);
  gl2lds16(pB0, wsl + SLOT + 16384);
  pA0 += BK; pA1 += BK; pB0 += BK;   // now at tile-2 source offset

  // Fragment addressing. A frag: lane holds A[m=lr][k=kq*8+j]; LDS row = 64 B.
  const int w   = tid >> 6;
  const int l   = tid & 63;
  const int wm  = w >> 1, wn = w & 1;            // 4 x 2 wave grid
  const int lr  = l & 15;
  const int kq  = l >> 4;
  const int kqs = kq ^ ((lr >> 1) & 3);          // bank-conflict swizzle
  const char* aBase = (const char*)lds + (wm * 64 + lr) * 64 + kqs * 16;
  const char* bBase = (const char*)lds + 16384 + (wn * 64 + lr) * 64 + kqs * 16;

  // Tile 0 arrival: own 3 oldest loads done (tile 1's may stay in flight).
  asm volatile("s_waitcnt vmcnt(3)" ::: "memory");
  __builtin_amdgcn_s_barrier();

  f32x4 acc[4][4] = {};
  int rOff = 0;               // read slot byte offset (t % 3)
  int sOff = 2 * SLOT;        // stage slot byte offset ((t+2) % 3)

  for (int t = 0; t < KTILES; ++t) {
    // Issue next prefetch first (maximizes cover; 3 VMEM issues are cheap).
    if (t < KTILES - 2) {
      char* d = wsl + sOff;
      gl2lds16(pA0, d);  gl2lds16(pA1, d + 8192);  gl2lds16(pB0, d + 16384);
      pA0 += BK; pA1 += BK; pB0 += BK;
      sOff = (sOff == (NBUF - 1) * SLOT) ? 0 : sOff + SLOT;
    }

    const char* aB = aBase + rOff;
    const char* bB = bBase + rOff;
    rOff = (rOff == (NBUF - 1) * SLOT) ? 0 : rOff + SLOT;

    bf16_8 af[4], bf[4];
#pragma unroll
    for (int i = 0; i < 4; ++i) af[i] = *(const bf16_8*)(aB + i * 1024);  // rows i*16
#pragma unroll
    for (int i = 0; i < 4; ++i) bf[i] = *(const bf16_8*)(bB + i * 1024);  // cols i*16

#pragma unroll
    for (int am = 0; am < 4; ++am)
#pragma unroll
      for (int bn = 0; bn < 4; ++bn)
        acc[am][bn] = __builtin_amdgcn_mfma_f32_16x16x32_bf16(
            af[am], bf[bn], acc[am][bn], 0, 0, 0);

    // Arrival of tile t+1 for next iteration; never drain until the tail.
    if (t < KTILES - 2)       { asm volatile("s_waitcnt vmcnt(3)" ::: "memory"); }
    else if (t == KTILES - 2) { asm volatile("s_waitcnt vmcnt(0)" ::: "memory"); }
    if (t < KTILES - 1) __builtin_amdgcn_s_barrier();
  }

  // Epilogue: C/D layout col=lane&15, row=(lane>>4)*4+reg.
  // Plain bf16 stores, ungated; gate applied in combine kernel.
  const int colBase = nt * BN + wn * 64 + lr;
  const int rq = kq * 4;
#pragma unroll
  for (int am = 0; am < 4; ++am) {
#pragma unroll
    for (int v = 0; v < 4; ++v) {
      int rl = wm * 64 + am * 16 + rq + v;
      int f  = sF[rl];
      if (f < 0) continue;
      __bf16* row = flat + (size_t)f * DOUT + colBase;
#pragma unroll
      for (int bn = 0; bn < 4; ++bn)
        row[bn * 16] = (__bf16)acc[am][bn][v];
    }
  }
}

// out[n, :] = g[2n]*flat[2n, :] + g[2n+1]*flat[2n+1, :]
__global__ __launch_bounds__(256)
void combine(const __bf16* __restrict__ flat, const float* __restrict__ gates,
             float* __restrict__ out) {
  const int n = blockIdx.x;
  const int c = threadIdx.x * 8;
  bf16_8 y0 = *(const bf16_8*)(flat + (size_t)(2 * n)     * DOUT + c);
  bf16_8 y1 = *(const bf16_8*)(flat + (size_t)(2 * n + 1) * DOUT + c);
  const float2 g = *(const float2*)(gates + 2 * n);
  float o[8];
#pragma unroll
  for (int j = 0; j < 8; ++j)
    o[j] = g.x * (float)y0[j] + g.y * (float)y1[j];
  float4* dst = (float4*)(out + (size_t)n * DOUT + c);
  dst[0] = *(float4*)&o[0];
  dst[1] = *(float4*)&o[4];
}

extern "C" void kernel_launch(void* const* d_in, const int* in_sizes, int n_in,
                              void* d_out, int out_size, void* d_ws, size_t ws_size,
                              hipStream_t stream) {
  const float* inputs = (const float*)d_in[0];   // [8192, 2048]
  const float* ew     = (const float*)d_in[1];   // [8, 2048, 2048] (E, out, in)
  const float* gates  = (const float*)d_in[2];   // [8192, 2]
  const int*   ssi    = (const int*)d_in[5];     // sorted_scattered_idxs [16384]
  const int*   offs   = (const int*)d_in[6];     // expert_offsets [8]
  float* out = (float*)d_out;

  // ws layout: bf16 W (64 MB) | bf16 X (32 MB) | bf16 flat out (64 MB)
  __bf16* wsW = (__bf16*)d_ws;
  __bf16* wsX = wsW + (size_t)NEXP * DOUT * DIN;
  __bf16* wsF = wsX + (size_t)NTOK * DIN;

  const int n8w = NEXP * DOUT * DIN / 8;   // 4194304 -> 16384 blocks
  const int n8x = NTOK * DIN / 8;          // 2097152 ->  8192 blocks
  const int nWb = n8w / 256, nXb = n8x / 256;
  cvt_all<<<nWb + nXb, 256, 0, stream>>>((const float4*)ew, (uint4*)wsW,
                                         (const float4*)inputs, (uint4*)wsX, nWb);

  // max M-tiles = 64 + 8 (per-expert ceil padding), 16 N-tiles of 128
  moe_gemm<<<72 * 16, 512, 0, stream>>>(wsX, wsW, ssi, offs, wsF);
  combine<<<NTOK, 256, 0, stream>>>(wsF, gates, out);
}